// Round 20
// baseline (122.308 us; speedup 1.0000x reference)
//
#include <hip/hip_runtime.h>
#include <hip/hip_bf16.h>
#include <cstdint>

// GATGraphRegressor: 2-layer GAT (4-head then 1-head) + global mean pool + linear.
// 6 dispatches:
//  init(cursor=0) -> {sgemm_scores<4> ∥ fill} -> agg4 -> sgemm_scores<1> ->
//   agg1 -> finalize
//  - GEMMs: float4/ushort4 vectorized staging, register-staged software
//    pipeline (prefetch tile k+1 during compute of tile k); sgemm1 uses
//    32-row tiles (626 blocks) to fix 1.2-block/CU tail imbalance.
//  - h1/h2/out1 BF16; scores from f32 registers in GEMM epilogue.
//  - Fixed-stride edge slots col[v*64+j]; cursor == degree. No col init:
//    aggs mask by (j+i < deg) and clamp stale/poison indices.
//  - agg: XCD-pinned slices (slice==head for conv1), 16 cq-lanes x 4
//    nodes/wave, col prefetch.

__device__ __forceinline__ float leaky02(float x) { return x > 0.f ? x : 0.2f * x; }
__device__ __forceinline__ float eluf(float x) { return x > 0.f ? x : expm1f(x); }
__device__ __forceinline__ float bf2f(unsigned short u) {
    return __uint_as_float((unsigned)u << 16);
}
__device__ __forceinline__ unsigned short f2bf(float f) {
    unsigned x = __float_as_uint(f);
    return (unsigned short)((x + 0x7FFF + ((x >> 16) & 1)) >> 16);
}
__device__ __forceinline__ float4 cv4(ushort4 u) {
    return make_float4(bf2f(u.x), bf2f(u.y), bf2f(u.z), bf2f(u.w));
}

// ---------------- init: cursor = 0 (80KB only; col needs no init) ----------------
__global__ void init_kernel(int4* __restrict__ p, int n4) {
    int i = blockIdx.x * blockDim.x + threadIdx.x;
    if (i < n4) p[i] = make_int4(0, 0, 0, 0);
}

// ---------------- SGEMM + fused scores (pipelined, vectorized) ----------------
// MT rows/thread (R = 16*MT block rows); AT = float or ushort(bf16).
// sT: transposed per-head planes sT[h*M+v]; dS,wself interleaved [v*H+h].
template <int H, int MT, typename AT>
__device__ __forceinline__ void sgemm_scores_body(
    const AT* __restrict__ A, const float* __restrict__ B,
    unsigned short* __restrict__ C, int M, int K,
    const float* __restrict__ asrc, const float* __restrict__ adst,
    float* __restrict__ sT, float* __restrict__ dS, float* __restrict__ wself,
    int bx, int by, float* As_, float* Bs_) {
    constexpr int Nc = H * 64;
    constexpr int R = MT * 16;
    constexpr int ACH = R / 32;  // 4-elem chunks per thread for the A tile
    float (*As)[68] = (float(*)[68])As_;
    float (*Bs)[68] = (float(*)[68])Bs_;
    const int tid = threadIdx.x;
    const int bm = bx * R, bn = by * 64;
    const int ty = tid >> 4, tx = tid & 15;
    float acc[MT][4] = {};

    int am[ACH], ak[ACH];
#pragma unroll
    for (int i = 0; i < ACH; i++) {
        int c = tid + 256 * i;
        am[i] = c >> 3;
        ak[i] = (c & 7) * 4;
    }
    float4 ga[ACH];
    ushort4 ga16[ACH];
    float4 gb[2];

    auto loadT = [&](int k0) {
#pragma unroll
        for (int i = 0; i < ACH; i++) {
            int gm = bm + am[i];
            if (gm >= M) gm = 0;
            if constexpr (sizeof(AT) == 4)
                ga[i] = *(const float4*)&A[(size_t)gm * K + k0 + ak[i]];
            else
                ga16[i] = *(const ushort4*)&A[(size_t)gm * K + k0 + ak[i]];
        }
#pragma unroll
        for (int i = 0; i < 2; i++) {
            int c = tid + 256 * i;
            gb[i] = *(const float4*)&B[(size_t)(k0 + (c >> 4)) * Nc + bn + (c & 15) * 4];
        }
    };
    auto storeT = [&]() {
#pragma unroll
        for (int i = 0; i < ACH; i++) {
            if constexpr (sizeof(AT) == 4) {
                As[ak[i] + 0][am[i]] = ga[i].x;
                As[ak[i] + 1][am[i]] = ga[i].y;
                As[ak[i] + 2][am[i]] = ga[i].z;
                As[ak[i] + 3][am[i]] = ga[i].w;
            } else {
                As[ak[i] + 0][am[i]] = bf2f(ga16[i].x);
                As[ak[i] + 1][am[i]] = bf2f(ga16[i].y);
                As[ak[i] + 2][am[i]] = bf2f(ga16[i].z);
                As[ak[i] + 3][am[i]] = bf2f(ga16[i].w);
            }
        }
#pragma unroll
        for (int i = 0; i < 2; i++) {
            int c = tid + 256 * i;
            *(float4*)&Bs[c >> 4][(c & 15) * 4] = gb[i];
        }
    };

    loadT(0);
    for (int k0 = 0; k0 < K; k0 += 32) {
        __syncthreads();  // previous compute done reading LDS
        storeT();
        __syncthreads();
        if (k0 + 32 < K) loadT(k0 + 32);  // prefetch next tile into regs
#pragma unroll
        for (int kk = 0; kk < 32; kk++) {
            float av[MT];
            if constexpr (MT == 4) {
                float4 a4 = *(const float4*)&As[kk][ty * 4];
                av[0] = a4.x; av[1] = a4.y; av[2] = a4.z; av[3] = a4.w;
            } else {
                float2 a2 = *(const float2*)&As[kk][ty * 2];
                av[0] = a2.x; av[1] = a2.y;
            }
            float4 b4 = *(const float4*)&Bs[kk][tx * 4];
            float bv[4] = {b4.x, b4.y, b4.z, b4.w};
#pragma unroll
            for (int r = 0; r < MT; r++)
#pragma unroll
                for (int c2 = 0; c2 < 4; c2++) acc[r][c2] += av[r] * bv[c2];
        }
    }
    const int h = by;
    float sr[MT], dr[MT];
#pragma unroll
    for (int r = 0; r < MT; r++) {
        float s = 0.f, d = 0.f;
#pragma unroll
        for (int c2 = 0; c2 < 4; c2++) {
            float hv = acc[r][c2];
            s += hv * asrc[h * 64 + tx * 4 + c2];
            d += hv * adst[h * 64 + tx * 4 + c2];
        }
        sr[r] = s;
        dr[r] = d;
    }
#pragma unroll
    for (int off = 1; off <= 8; off <<= 1) {
#pragma unroll
        for (int r = 0; r < MT; r++) {
            sr[r] += __shfl_xor(sr[r], off);
            dr[r] += __shfl_xor(dr[r], off);
        }
    }
#pragma unroll
    for (int r = 0; r < MT; r++) {
        int gm = bm + ty * MT + r;
        if (gm < M) {
            ushort4 o;
            o.x = f2bf(acc[r][0]);
            o.y = f2bf(acc[r][1]);
            o.z = f2bf(acc[r][2]);
            o.w = f2bf(acc[r][3]);
            *(ushort4*)&C[(size_t)gm * Nc + bn + tx * 4] = o;
            if (tx == 0) {
                sT[(size_t)h * M + gm] = sr[r];
                dS[gm * H + h] = dr[r];
                wself[gm * H + h] = __expf(leaky02(sr[r] + dr[r]));
            }
        }
    }
}

// ---------------- dispatch B: sgemm_scores<4> blocks ∥ fill blocks ----------------
__global__ __launch_bounds__(256) void fused_sgemm4_fill_kernel(
    const float* __restrict__ A, const float* __restrict__ B,
    unsigned short* __restrict__ C, int M, int K,
    const float* __restrict__ asrc, const float* __restrict__ adst,
    float* __restrict__ sT, float* __restrict__ dS, float* __restrict__ wself,
    int GBX, int GB1, const int* __restrict__ src, const int* __restrict__ dst,
    int* __restrict__ cursor, int* __restrict__ col, int E) {
    __shared__ __align__(16) float As_[32][68];
    __shared__ __align__(16) float Bs_[32][68];
    const int b = blockIdx.x;
    if (b >= GB1) {
        int e = (b - GB1) * 256 + threadIdx.x;
        if (e < E) {
            int d = dst[e];
            int p = atomicAdd(&cursor[d], 1);
            if (p < 64) col[(d << 6) + p] = src[e];
        }
        return;
    }
    sgemm_scores_body<4, 4, float>(A, B, C, M, K, asrc, adst, sT, dS, wself,
                                   b % GBX, b / GBX, &As_[0][0], &Bs_[0][0]);
}

__global__ __launch_bounds__(256) void sgemm_scores1_kernel(
    const unsigned short* __restrict__ A, const float* __restrict__ B,
    unsigned short* __restrict__ C, int M, int K,
    const float* __restrict__ asrc, const float* __restrict__ adst,
    float* __restrict__ sT, float* __restrict__ dS, float* __restrict__ wself) {
    __shared__ __align__(16) float As_[32][68];
    __shared__ __align__(16) float Bs_[32][68];
    sgemm_scores_body<1, 2, unsigned short>(A, B, C, M, K, asrc, adst, sT, dS, wself,
                                            blockIdx.x, 0, &As_[0][0], &Bs_[0][0]);
}

// ---------------- conv1 aggregation: bf16 h1, slice==head, 4 nodes/wave ----------
__global__ __launch_bounds__(256) void gat_agg4_kernel(
    const unsigned short* __restrict__ h1, const float* __restrict__ sT,
    const float* __restrict__ dsc, const float* __restrict__ wself,
    const int* __restrict__ cursor, const int* __restrict__ col,
    const float* __restrict__ bias, unsigned short* __restrict__ out, int N) {
    const int slice = blockIdx.x & 3;              // == head
    const int sub = (blockIdx.x >> 2) & 1;
    const int vgrp = (blockIdx.x >> 3) * 2 + sub;
    const int lane = threadIdx.x & 63;
    const int cq = lane & 15;
    const int vidx = vgrp * 16 + (threadIdx.x >> 6) * 4 + (lane >> 4);
    const bool valid = vidx < N;
    const int v = min(vidx, N - 1);
    const int deg = min(cursor[v], 64);
    const int base = v << 6;
    const int ch = slice * 64 + cq * 4;
    const float* __restrict__ sTh = sT + (size_t)slice * N;
    const unsigned short* __restrict__ hp = h1 + slice * 64 + cq * 4;
    const float dvh = dsc[v * 4 + slice];
    float wsf = wself[v * 4 + slice];
    float den = wsf;
    float4 hv = cv4(*(const ushort4*)(hp + ((size_t)v << 8)));
    float4 acc = make_float4(wsf * hv.x, wsf * hv.y, wsf * hv.z, wsf * hv.w);
    int4 c4 = *(const int4*)&col[base];
    for (int j = 0; j < deg; j += 4) {
        int4 cc = c4;
        c4 = *(const int4*)&col[base + j + 4];  // prefetch (in-bounds in carve)
        unsigned i0 = (unsigned)max(cc.x, 0), i1 = (unsigned)max(cc.y, 0);
        unsigned i2 = (unsigned)max(cc.z, 0), i3 = (unsigned)max(cc.w, 0);
        float4 h0 = cv4(*(const ushort4*)(hp + ((size_t)i0 << 8)));
        float4 h1v = cv4(*(const ushort4*)(hp + ((size_t)i1 << 8)));
        float4 h2v = cv4(*(const ushort4*)(hp + ((size_t)i2 << 8)));
        float4 h3v = cv4(*(const ushort4*)(hp + ((size_t)i3 << 8)));
        float w0 = (j + 0 < deg) ? __expf(leaky02(sTh[i0] + dvh)) : 0.f;
        float w1 = (j + 1 < deg) ? __expf(leaky02(sTh[i1] + dvh)) : 0.f;
        float w2 = (j + 2 < deg) ? __expf(leaky02(sTh[i2] + dvh)) : 0.f;
        float w3 = (j + 3 < deg) ? __expf(leaky02(sTh[i3] + dvh)) : 0.f;
        den += w0 + w1 + w2 + w3;
        acc.x += w0 * h0.x + w1 * h1v.x + w2 * h2v.x + w3 * h3v.x;
        acc.y += w0 * h0.y + w1 * h1v.y + w2 * h2v.y + w3 * h3v.y;
        acc.z += w0 * h0.z + w1 * h1v.z + w2 * h2v.z + w3 * h3v.z;
        acc.w += w0 * h0.w + w1 * h1v.w + w2 * h2v.w + w3 * h3v.w;
    }
    if (valid) {
        float4 b4 = *(const float4*)&bias[ch];
        float inv = 1.f / den;
        ushort4 o;
        o.x = f2bf(eluf(acc.x * inv + b4.x));
        o.y = f2bf(eluf(acc.y * inv + b4.y));
        o.z = f2bf(eluf(acc.z * inv + b4.z));
        o.w = f2bf(eluf(acc.w * inv + b4.w));
        *(ushort4*)&out[(size_t)v * 256 + ch] = o;  // bf16 out1
    }
}

// ---------------- conv2 aggregation (bf16 h2, one line/node) + Wlin dot ----------
__global__ __launch_bounds__(256) void gat_agg1_kernel(
    const unsigned short* __restrict__ h2, const float* __restrict__ sT,
    const float* __restrict__ dsc, const float* __restrict__ wself,
    const int* __restrict__ cursor, const int* __restrict__ col,
    const float* __restrict__ bias, const float* __restrict__ Wlin,
    float* __restrict__ pn, int N) {
    const int lane = threadIdx.x & 63;
    const int cq = lane & 15;
    const int vidx = blockIdx.x * 16 + (threadIdx.x >> 6) * 4 + (lane >> 4);
    const bool valid = vidx < N;
    const int v = min(vidx, N - 1);
    const int deg = min(cursor[v], 64);
    const int base = v << 6;
    const unsigned short* __restrict__ hp = h2 + cq * 4;
    const float dv = dsc[v];
    float wsf = wself[v];
    float den = wsf;
    float4 hv = cv4(*(const ushort4*)(hp + ((size_t)v << 6)));
    float4 acc = make_float4(wsf * hv.x, wsf * hv.y, wsf * hv.z, wsf * hv.w);
    int4 c4 = *(const int4*)&col[base];
    for (int j = 0; j < deg; j += 4) {
        int4 cc = c4;
        c4 = *(const int4*)&col[base + j + 4];
        unsigned i0 = (unsigned)max(cc.x, 0), i1 = (unsigned)max(cc.y, 0);
        unsigned i2 = (unsigned)max(cc.z, 0), i3 = (unsigned)max(cc.w, 0);
        float4 h0 = cv4(*(const ushort4*)(hp + ((size_t)i0 << 6)));
        float4 h1v = cv4(*(const ushort4*)(hp + ((size_t)i1 << 6)));
        float4 h2v = cv4(*(const ushort4*)(hp + ((size_t)i2 << 6)));
        float4 h3v = cv4(*(const ushort4*)(hp + ((size_t)i3 << 6)));
        float w0 = (j + 0 < deg) ? __expf(leaky02(sT[i0] + dv)) : 0.f;
        float w1 = (j + 1 < deg) ? __expf(leaky02(sT[i1] + dv)) : 0.f;
        float w2 = (j + 2 < deg) ? __expf(leaky02(sT[i2] + dv)) : 0.f;
        float w3 = (j + 3 < deg) ? __expf(leaky02(sT[i3] + dv)) : 0.f;
        den += w0 + w1 + w2 + w3;
        acc.x += w0 * h0.x + w1 * h1v.x + w2 * h2v.x + w3 * h3v.x;
        acc.y += w0 * h0.y + w1 * h1v.y + w2 * h2v.y + w3 * h3v.y;
        acc.z += w0 * h0.z + w1 * h1v.z + w2 * h2v.z + w3 * h3v.z;
        acc.w += w0 * h0.w + w1 * h1v.w + w2 * h2v.w + w3 * h3v.w;
    }
    float4 b4 = *(const float4*)&bias[cq * 4];
    float4 wl = *(const float4*)&Wlin[cq * 4];
    float inv = 1.f / den;
    float p = eluf(acc.x * inv + b4.x) * wl.x + eluf(acc.y * inv + b4.y) * wl.y +
              eluf(acc.z * inv + b4.z) * wl.z + eluf(acc.w * inv + b4.w) * wl.w;
    p += __shfl_xor(p, 1);
    p += __shfl_xor(p, 2);
    p += __shfl_xor(p, 4);
    p += __shfl_xor(p, 8);
    if (valid && cq == 0) pn[v] = p;
}

// ---------------- finalize: one wave per graph, segmented sum over sorted batch ----
__global__ __launch_bounds__(64) void finalize_kernel(const float* __restrict__ pn,
                                                      const int* __restrict__ batch,
                                                      const float* __restrict__ blin,
                                                      float* __restrict__ outp, int N, int G) {
    const int g = blockIdx.x;
    const int lane = threadIdx.x;
    int lo = 0, hi = N;
    while (lo < hi) { int mid = (lo + hi) >> 1; if (batch[mid] < g) lo = mid + 1; else hi = mid; }
    int lo2 = lo, hi2 = N;
    while (lo2 < hi2) { int mid = (lo2 + hi2) >> 1; if (batch[mid] < g + 1) lo2 = mid + 1; else hi2 = mid; }
    float s = 0.f;
    for (int i = lo + lane; i < hi2; i += 64) s += pn[i];
#pragma unroll
    for (int off = 32; off > 0; off >>= 1) s += __shfl_xor(s, off);
    if (lane == 0) {
        float cnt = (float)(hi2 - lo);
        outp[g] = s / fmaxf(cnt, 1.f) + blin[0];
    }
}

extern "C" void kernel_launch(void* const* d_in, const int* in_sizes, int n_in,
                              void* d_out, int out_size, void* d_ws, size_t ws_size,
                              hipStream_t stream) {
    const float* x      = (const float*)d_in[0];
    const int*   ei     = (const int*)d_in[1];
    const int*   batch  = (const int*)d_in[2];
    const float* W1     = (const float*)d_in[3];
    const float* a_src1 = (const float*)d_in[4];
    const float* a_dst1 = (const float*)d_in[5];
    const float* b1     = (const float*)d_in[6];
    const float* W2     = (const float*)d_in[7];
    const float* a_src2 = (const float*)d_in[8];
    const float* a_dst2 = (const float*)d_in[9];
    const float* b2     = (const float*)d_in[10];
    const float* Wlin   = (const float*)d_in[11];
    const float* blin   = (const float*)d_in[12];

    const int N = in_sizes[2];
    const int E = in_sizes[1] / 2;
    const int G = out_size;
    const int* src = ei;
    const int* dst = ei + E;

    char* ws = (char*)d_ws;
    size_t off = 0;
    auto carve = [&](size_t bytes) -> char* {
        char* p = ws + off;
        off = (off + bytes + 255) & ~(size_t)255;
        return p;
    };
    unsigned short* h1   = (unsigned short*)carve((size_t)N * 256 * 2);  // bf16
    unsigned short* out1 = (unsigned short*)carve((size_t)N * 256 * 2);  // bf16
    unsigned short* h2   = (unsigned short*)carve((size_t)N * 64 * 2);   // bf16
    float* sT1     = (float*)carve((size_t)4 * N * 4);  // [H][N]
    float* d1      = (float*)carve((size_t)N * 4 * 4);
    float* wself1  = (float*)carve((size_t)N * 4 * 4);
    float* sT2     = (float*)carve((size_t)N * 4);
    float* d2      = (float*)carve((size_t)N * 4);
    float* wself2  = (float*)carve((size_t)N * 4);
    int*   colcur  = (int*)carve(((size_t)N * 64 + N) * 4);  // col | cursor
    float* pn      = (float*)carve((size_t)N * 4);
    int* col = colcur;
    int* cursor = colcur + (size_t)N * 64;

    const int GBX = (N + 63) / 64;       // 64-row tiles for sgemm4
    const int GB1 = GBX * 4;
    const int GBX1 = (N + 31) / 32;      // 32-row tiles for sgemm1
    const int curN4 = (N + 3) / 4;
    const int fillBlocks = (E + 255) / 256;

    // 1: init cursor=0 (col needs no init: aggs mask by degree)
    init_kernel<<<(curN4 + 255) / 256, 256, 0, stream>>>((int4*)cursor, curN4);
    // 2: conv1 GEMM + scores (bf16 h1) ∥ fill
    fused_sgemm4_fill_kernel<<<GB1 + fillBlocks, 256, 0, stream>>>(
        x, W1, h1, N, 128, a_src1, a_dst1, sT1, d1, wself1,
        GBX, GB1, src, dst, cursor, col, E);
    // 3: conv1 aggregation (bf16 out1)
    const int nodeGroups32 = (N + 31) / 32;
    gat_agg4_kernel<<<8 * nodeGroups32, 256, 0, stream>>>(h1, sT1, d1, wself1, cursor, col,
                                                          b1, out1, N);
    // 4: conv2 GEMM + scores (bf16 A, bf16 h2), 32-row tiles
    sgemm_scores1_kernel<<<GBX1, 256, 0, stream>>>(
        out1, W2, h2, N, 256, a_src2, a_dst2, sT2, d2, wself2);
    // 5: conv2 aggregation + Wlin dot
    gat_agg1_kernel<<<(N + 15) / 16, 256, 0, stream>>>(h2, sT2, d2, wself2, cursor, col,
                                                       b2, Wlin, pn, N);
    // 6: pooled mean + linear
    finalize_kernel<<<G, 64, 0, stream>>>(pn, batch, blin, (float*)d_out, N, G);
}

// Round 21
// 114.438 us; speedup vs baseline: 1.0688x; 1.0688x over previous
//
#include <hip/hip_runtime.h>
#include <hip/hip_bf16.h>
#include <cstdint>

// GATGraphRegressor: 2-layer GAT (4-head then 1-head) + global mean pool + linear.
// 6 dispatches:
//  init(col=-1,cursor=0) -> {sgemm_scores<4> ∥ fill} -> agg4 ->
//   sgemm_scores<1> (bf16 A) -> agg1 -> finalize
//  - R19 structure (empirical best). R20's register-staged GEMM pipeline and
//    col-init drop both regressed -> reverted. Only change vs R19: B-tile
//    staging uses 2 float4 loads/stores (was 8 scalar) - same layout/barriers.
//  - h1/h2/out1 BF16; scores from f32 registers in GEMM epilogue.
//  - Fixed-stride edge slots col[v*64+j]; cursor == degree; sentinel col=-1.
//  - agg: XCD-pinned slices (slice==head for conv1), 16 cq-lanes x 4
//    nodes/wave, col prefetch.

__device__ __forceinline__ float leaky02(float x) { return x > 0.f ? x : 0.2f * x; }
__device__ __forceinline__ float eluf(float x) { return x > 0.f ? x : expm1f(x); }
__device__ __forceinline__ float bf2f(unsigned short u) {
    return __uint_as_float((unsigned)u << 16);
}
__device__ __forceinline__ unsigned short f2bf(float f) {
    unsigned x = __float_as_uint(f);
    return (unsigned short)((x + 0x7FFF + ((x >> 16) & 1)) >> 16);
}
__device__ __forceinline__ float4 cv4(ushort4 u) {
    return make_float4(bf2f(u.x), bf2f(u.y), bf2f(u.z), bf2f(u.w));
}
__device__ __forceinline__ float ldA(const float* p) { return *p; }
__device__ __forceinline__ float ldA(const unsigned short* p) { return bf2f(*p); }

// ---------------- init: col=-1, cursor=0 ----------------
__global__ void init_kernel(int4* __restrict__ p, int colN4, int totN4) {
    int i = blockIdx.x * blockDim.x + threadIdx.x;
    if (i < totN4)
        p[i] = (i < colN4) ? make_int4(-1, -1, -1, -1) : make_int4(0, 0, 0, 0);
}

// ---------------- SGEMM + fused scores (device body), bf16 C, AT A ----------------
template <int H, typename AT>
__device__ __forceinline__ void sgemm_scores_body(
    const AT* __restrict__ A, const float* __restrict__ B,
    unsigned short* __restrict__ C, int M, int K,
    const float* __restrict__ asrc, const float* __restrict__ adst,
    float* __restrict__ sT, float* __restrict__ dS, float* __restrict__ wself,
    int bx, int by, float* As_, float* Bs_) {
    constexpr int Nc = H * 64;
    float (*As)[68] = (float(*)[68])As_;
    float (*Bs)[68] = (float(*)[68])Bs_;
    const int tid = threadIdx.x;
    const int bm = bx * 64, bn = by * 64;
    const int ty = tid >> 4, tx = tid & 15;
    float acc[4][4] = {};
    for (int k0 = 0; k0 < K; k0 += 32) {
#pragma unroll
        for (int i = 0; i < 8; i++) {
            int idx = tid + i * 256;
            int m = idx >> 5, kk = idx & 31;
            int gm = bm + m;
            if (gm >= M) gm = 0;
            As[kk][m] = ldA(&A[(size_t)gm * K + k0 + kk]);
        }
#pragma unroll
        for (int i = 0; i < 2; i++) {
            int c = tid + i * 256;               // 0..511: 32 rows x 16 float4
            int kk = c >> 4, n4 = (c & 15) * 4;
            *(float4*)&Bs[kk][n4] =
                *(const float4*)&B[(size_t)(k0 + kk) * Nc + bn + n4];
        }
        __syncthreads();
#pragma unroll
        for (int kk = 0; kk < 32; kk++) {
            float4 a4 = *(const float4*)&As[kk][ty * 4];
            float4 b4 = *(const float4*)&Bs[kk][tx * 4];
            float av[4] = {a4.x, a4.y, a4.z, a4.w};
            float bv[4] = {b4.x, b4.y, b4.z, b4.w};
#pragma unroll
            for (int r = 0; r < 4; r++)
#pragma unroll
                for (int c2 = 0; c2 < 4; c2++) acc[r][c2] += av[r] * bv[c2];
        }
        __syncthreads();
    }
    const int h = by;
    float sr[4], dr[4];
#pragma unroll
    for (int r = 0; r < 4; r++) {
        float s = 0.f, d = 0.f;
#pragma unroll
        for (int c2 = 0; c2 < 4; c2++) {
            float hv = acc[r][c2];
            s += hv * asrc[h * 64 + tx * 4 + c2];
            d += hv * adst[h * 64 + tx * 4 + c2];
        }
        sr[r] = s;
        dr[r] = d;
    }
#pragma unroll
    for (int off = 1; off <= 8; off <<= 1) {
#pragma unroll
        for (int r = 0; r < 4; r++) {
            sr[r] += __shfl_xor(sr[r], off);
            dr[r] += __shfl_xor(dr[r], off);
        }
    }
#pragma unroll
    for (int r = 0; r < 4; r++) {
        int gm = bm + ty * 4 + r;
        if (gm < M) {
            ushort4 o;
            o.x = f2bf(acc[r][0]);
            o.y = f2bf(acc[r][1]);
            o.z = f2bf(acc[r][2]);
            o.w = f2bf(acc[r][3]);
            *(ushort4*)&C[(size_t)gm * Nc + bn + tx * 4] = o;
            if (tx == 0) {
                sT[(size_t)h * M + gm] = sr[r];
                dS[gm * H + h] = dr[r];
                wself[gm * H + h] = __expf(leaky02(sr[r] + dr[r]));
            }
        }
    }
}

// ---------------- dispatch B: sgemm_scores<4> blocks ∥ fill blocks ----------------
__global__ __launch_bounds__(256) void fused_sgemm4_fill_kernel(
    const float* __restrict__ A, const float* __restrict__ B,
    unsigned short* __restrict__ C, int M, int K,
    const float* __restrict__ asrc, const float* __restrict__ adst,
    float* __restrict__ sT, float* __restrict__ dS, float* __restrict__ wself,
    int GBX, int GB1, const int* __restrict__ src, const int* __restrict__ dst,
    int* __restrict__ cursor, int* __restrict__ col, int E) {
    __shared__ __align__(16) float As_[32][68];
    __shared__ __align__(16) float Bs_[32][68];
    const int b = blockIdx.x;
    if (b >= GB1) {
        int e = (b - GB1) * 256 + threadIdx.x;
        if (e < E) {
            int d = dst[e];
            int p = atomicAdd(&cursor[d], 1);
            if (p < 64) col[(d << 6) + p] = src[e];
        }
        return;
    }
    sgemm_scores_body<4, float>(A, B, C, M, K, asrc, adst, sT, dS, wself,
                                b % GBX, b / GBX, &As_[0][0], &Bs_[0][0]);
}

__global__ __launch_bounds__(256) void sgemm_scores1_kernel(
    const unsigned short* __restrict__ A, const float* __restrict__ B,
    unsigned short* __restrict__ C, int M, int K,
    const float* __restrict__ asrc, const float* __restrict__ adst,
    float* __restrict__ sT, float* __restrict__ dS, float* __restrict__ wself) {
    __shared__ __align__(16) float As_[32][68];
    __shared__ __align__(16) float Bs_[32][68];
    sgemm_scores_body<1, unsigned short>(A, B, C, M, K, asrc, adst, sT, dS, wself,
                                         blockIdx.x, 0, &As_[0][0], &Bs_[0][0]);
}

// ---------------- conv1 aggregation: bf16 h1, slice==head, 4 nodes/wave ----------
__global__ __launch_bounds__(256) void gat_agg4_kernel(
    const unsigned short* __restrict__ h1, const float* __restrict__ sT,
    const float* __restrict__ dsc, const float* __restrict__ wself,
    const int* __restrict__ cursor, const int* __restrict__ col,
    const float* __restrict__ bias, unsigned short* __restrict__ out, int N) {
    const int slice = blockIdx.x & 3;              // == head
    const int sub = (blockIdx.x >> 2) & 1;
    const int vgrp = (blockIdx.x >> 3) * 2 + sub;
    const int lane = threadIdx.x & 63;
    const int cq = lane & 15;
    const int vidx = vgrp * 16 + (threadIdx.x >> 6) * 4 + (lane >> 4);
    const bool valid = vidx < N;
    const int v = min(vidx, N - 1);
    const int deg = min(cursor[v], 64);
    const int base = v << 6;
    const int ch = slice * 64 + cq * 4;
    const float* __restrict__ sTh = sT + (size_t)slice * N;
    const unsigned short* __restrict__ hp = h1 + slice * 64 + cq * 4;
    const float dvh = dsc[v * 4 + slice];
    float wsf = wself[v * 4 + slice];
    float den = wsf;
    float4 hv = cv4(*(const ushort4*)(hp + ((size_t)v << 8)));
    float4 acc = make_float4(wsf * hv.x, wsf * hv.y, wsf * hv.z, wsf * hv.w);
    const int end4 = (deg + 3) & ~3;
    int4 c4 = *(const int4*)&col[base];
    for (int j = 0; j < end4; j += 4) {
        int4 cc = c4;
        c4 = *(const int4*)&col[base + j + 4];  // prefetch (in-bounds in carve)
        unsigned i0 = (unsigned)max(cc.x, 0), i1 = (unsigned)max(cc.y, 0);
        unsigned i2 = (unsigned)max(cc.z, 0), i3 = (unsigned)max(cc.w, 0);
        float4 h0 = cv4(*(const ushort4*)(hp + ((size_t)i0 << 8)));
        float4 h1v = cv4(*(const ushort4*)(hp + ((size_t)i1 << 8)));
        float4 h2v = cv4(*(const ushort4*)(hp + ((size_t)i2 << 8)));
        float4 h3v = cv4(*(const ushort4*)(hp + ((size_t)i3 << 8)));
        float w0 = (cc.x >= 0) ? __expf(leaky02(sTh[i0] + dvh)) : 0.f;
        float w1 = (cc.y >= 0) ? __expf(leaky02(sTh[i1] + dvh)) : 0.f;
        float w2 = (cc.z >= 0) ? __expf(leaky02(sTh[i2] + dvh)) : 0.f;
        float w3 = (cc.w >= 0) ? __expf(leaky02(sTh[i3] + dvh)) : 0.f;
        den += w0 + w1 + w2 + w3;
        acc.x += w0 * h0.x + w1 * h1v.x + w2 * h2v.x + w3 * h3v.x;
        acc.y += w0 * h0.y + w1 * h1v.y + w2 * h2v.y + w3 * h3v.y;
        acc.z += w0 * h0.z + w1 * h1v.z + w2 * h2v.z + w3 * h3v.z;
        acc.w += w0 * h0.w + w1 * h1v.w + w2 * h2v.w + w3 * h3v.w;
    }
    if (valid) {
        float4 b4 = *(const float4*)&bias[ch];
        float inv = 1.f / den;
        ushort4 o;
        o.x = f2bf(eluf(acc.x * inv + b4.x));
        o.y = f2bf(eluf(acc.y * inv + b4.y));
        o.z = f2bf(eluf(acc.z * inv + b4.z));
        o.w = f2bf(eluf(acc.w * inv + b4.w));
        *(ushort4*)&out[(size_t)v * 256 + ch] = o;  // bf16 out1
    }
}

// ---------------- conv2 aggregation (bf16 h2, one line/node) + Wlin dot ----------
__global__ __launch_bounds__(256) void gat_agg1_kernel(
    const unsigned short* __restrict__ h2, const float* __restrict__ sT,
    const float* __restrict__ dsc, const float* __restrict__ wself,
    const int* __restrict__ cursor, const int* __restrict__ col,
    const float* __restrict__ bias, const float* __restrict__ Wlin,
    float* __restrict__ pn, int N) {
    const int lane = threadIdx.x & 63;
    const int cq = lane & 15;
    const int vidx = blockIdx.x * 16 + (threadIdx.x >> 6) * 4 + (lane >> 4);
    const bool valid = vidx < N;
    const int v = min(vidx, N - 1);
    const int deg = min(cursor[v], 64);
    const int base = v << 6;
    const unsigned short* __restrict__ hp = h2 + cq * 4;
    const float dv = dsc[v];
    float wsf = wself[v];
    float den = wsf;
    float4 hv = cv4(*(const ushort4*)(hp + ((size_t)v << 6)));
    float4 acc = make_float4(wsf * hv.x, wsf * hv.y, wsf * hv.z, wsf * hv.w);
    const int end4 = (deg + 3) & ~3;
    int4 c4 = *(const int4*)&col[base];
    for (int j = 0; j < end4; j += 4) {
        int4 cc = c4;
        c4 = *(const int4*)&col[base + j + 4];
        unsigned i0 = (unsigned)max(cc.x, 0), i1 = (unsigned)max(cc.y, 0);
        unsigned i2 = (unsigned)max(cc.z, 0), i3 = (unsigned)max(cc.w, 0);
        float4 h0 = cv4(*(const ushort4*)(hp + ((size_t)i0 << 6)));
        float4 h1v = cv4(*(const ushort4*)(hp + ((size_t)i1 << 6)));
        float4 h2v = cv4(*(const ushort4*)(hp + ((size_t)i2 << 6)));
        float4 h3v = cv4(*(const ushort4*)(hp + ((size_t)i3 << 6)));
        float w0 = (cc.x >= 0) ? __expf(leaky02(sT[i0] + dv)) : 0.f;
        float w1 = (cc.y >= 0) ? __expf(leaky02(sT[i1] + dv)) : 0.f;
        float w2 = (cc.z >= 0) ? __expf(leaky02(sT[i2] + dv)) : 0.f;
        float w3 = (cc.w >= 0) ? __expf(leaky02(sT[i3] + dv)) : 0.f;
        den += w0 + w1 + w2 + w3;
        acc.x += w0 * h0.x + w1 * h1v.x + w2 * h2v.x + w3 * h3v.x;
        acc.y += w0 * h0.y + w1 * h1v.y + w2 * h2v.y + w3 * h3v.y;
        acc.z += w0 * h0.z + w1 * h1v.z + w2 * h2v.z + w3 * h3v.z;
        acc.w += w0 * h0.w + w1 * h1v.w + w2 * h2v.w + w3 * h3v.w;
    }
    float4 b4 = *(const float4*)&bias[cq * 4];
    float4 wl = *(const float4*)&Wlin[cq * 4];
    float inv = 1.f / den;
    float p = eluf(acc.x * inv + b4.x) * wl.x + eluf(acc.y * inv + b4.y) * wl.y +
              eluf(acc.z * inv + b4.z) * wl.z + eluf(acc.w * inv + b4.w) * wl.w;
    p += __shfl_xor(p, 1);
    p += __shfl_xor(p, 2);
    p += __shfl_xor(p, 4);
    p += __shfl_xor(p, 8);
    if (valid && cq == 0) pn[v] = p;
}

// ---------------- finalize: one wave per graph, segmented sum over sorted batch ----
__global__ __launch_bounds__(64) void finalize_kernel(const float* __restrict__ pn,
                                                      const int* __restrict__ batch,
                                                      const float* __restrict__ blin,
                                                      float* __restrict__ outp, int N, int G) {
    const int g = blockIdx.x;
    const int lane = threadIdx.x;
    int lo = 0, hi = N;
    while (lo < hi) { int mid = (lo + hi) >> 1; if (batch[mid] < g) lo = mid + 1; else hi = mid; }
    int lo2 = lo, hi2 = N;
    while (lo2 < hi2) { int mid = (lo2 + hi2) >> 1; if (batch[mid] < g + 1) lo2 = mid + 1; else hi2 = mid; }
    float s = 0.f;
    for (int i = lo + lane; i < hi2; i += 64) s += pn[i];
#pragma unroll
    for (int off = 32; off > 0; off >>= 1) s += __shfl_xor(s, off);
    if (lane == 0) {
        float cnt = (float)(hi2 - lo);
        outp[g] = s / fmaxf(cnt, 1.f) + blin[0];
    }
}

extern "C" void kernel_launch(void* const* d_in, const int* in_sizes, int n_in,
                              void* d_out, int out_size, void* d_ws, size_t ws_size,
                              hipStream_t stream) {
    const float* x      = (const float*)d_in[0];
    const int*   ei     = (const int*)d_in[1];
    const int*   batch  = (const int*)d_in[2];
    const float* W1     = (const float*)d_in[3];
    const float* a_src1 = (const float*)d_in[4];
    const float* a_dst1 = (const float*)d_in[5];
    const float* b1     = (const float*)d_in[6];
    const float* W2     = (const float*)d_in[7];
    const float* a_src2 = (const float*)d_in[8];
    const float* a_dst2 = (const float*)d_in[9];
    const float* b2     = (const float*)d_in[10];
    const float* Wlin   = (const float*)d_in[11];
    const float* blin   = (const float*)d_in[12];

    const int N = in_sizes[2];
    const int E = in_sizes[1] / 2;
    const int G = out_size;
    const int* src = ei;
    const int* dst = ei + E;

    char* ws = (char*)d_ws;
    size_t off = 0;
    auto carve = [&](size_t bytes) -> char* {
        char* p = ws + off;
        off = (off + bytes + 255) & ~(size_t)255;
        return p;
    };
    unsigned short* h1   = (unsigned short*)carve((size_t)N * 256 * 2);  // bf16
    unsigned short* out1 = (unsigned short*)carve((size_t)N * 256 * 2);  // bf16
    unsigned short* h2   = (unsigned short*)carve((size_t)N * 64 * 2);   // bf16
    float* sT1     = (float*)carve((size_t)4 * N * 4);  // [H][N]
    float* d1      = (float*)carve((size_t)N * 4 * 4);
    float* wself1  = (float*)carve((size_t)N * 4 * 4);
    float* sT2     = (float*)carve((size_t)N * 4);
    float* d2      = (float*)carve((size_t)N * 4);
    float* wself2  = (float*)carve((size_t)N * 4);
    int*   colcur  = (int*)carve(((size_t)N * 64 + N) * 4);  // col | cursor
    float* pn      = (float*)carve((size_t)N * 4);
    int* col = colcur;
    int* cursor = colcur + (size_t)N * 64;

    const int GBX = (N + 63) / 64;
    const int GB1 = GBX * 4;
    const int colN4 = (N * 64) / 4;
    const int totN4 = (N * 64 + N + 3) / 4;
    const int fillBlocks = (E + 255) / 256;

    // 1: init(col=-1, cursor=0)
    init_kernel<<<(totN4 + 255) / 256, 256, 0, stream>>>((int4*)colcur, colN4, totN4);
    // 2: conv1 GEMM + scores (bf16 h1) ∥ fill
    fused_sgemm4_fill_kernel<<<GB1 + fillBlocks, 256, 0, stream>>>(
        x, W1, h1, N, 128, a_src1, a_dst1, sT1, d1, wself1,
        GBX, GB1, src, dst, cursor, col, E);
    // 3: conv1 aggregation (bf16 out1)
    const int nodeGroups32 = (N + 31) / 32;
    gat_agg4_kernel<<<8 * nodeGroups32, 256, 0, stream>>>(h1, sT1, d1, wself1, cursor, col,
                                                          b1, out1, N);
    // 4: conv2 GEMM + scores (bf16 A, bf16 h2)
    sgemm_scores1_kernel<<<dim3(GBX, 1), 256, 0, stream>>>(
        out1, W2, h2, N, 256, a_src2, a_dst2, sT2, d2, wself2);
    // 5: conv2 aggregation + Wlin dot
    gat_agg1_kernel<<<(N + 15) / 16, 256, 0, stream>>>(h2, sT2, d2, wself2, cursor, col,
                                                       b2, Wlin, pn, N);
    // 6: pooled mean + linear
    finalize_kernel<<<G, 64, 0, stream>>>(pn, batch, blin, (float*)d_out, N, G);
}